// Round 3
// baseline (546.348 us; speedup 1.0000x reference)
//
#include <hip/hip_runtime.h>
#include <math.h>

// Problem constants
#define BB 8
#define TT 8192
#define FF 1024
#define HH 256
#define OO 2
#define MT 64               // rows per block
#define NBLK ((BB*TT)/MT)   // 1024 main blocks
#define PBAG (TT/MT)        // 128 blocks per bag
#define PSTR 260            // floats per partial record: [m, l, acc[256], pad2]

typedef __attribute__((ext_vector_type(8))) short bf16x8;
typedef __attribute__((ext_vector_type(4))) float f32x4;

__device__ __forceinline__ float b2f(unsigned short s) {
    union { unsigned u; float f; } v; v.u = ((unsigned)s) << 16; return v.f;
}
__device__ __forceinline__ unsigned short f2b(float f) {
    union { float f; unsigned u; } v; v.f = f;
    unsigned u = v.u;
    return (unsigned short)((u + 0x7fffu + ((u >> 16) & 1u)) >> 16);
}
__device__ __forceinline__ unsigned pk2(float a, float b) {
    return (unsigned)f2b(a) | ((unsigned)f2b(b) << 16);
}

// ---------------- prep: LDS-tiled transpose + bf16 convert ----------------
__global__ __launch_bounds__(256)
void mil_prep(const float* __restrict__ W1,
              const float* __restrict__ Wv,
              const float* __restrict__ Wu,
              unsigned short* __restrict__ W1t,
              unsigned short* __restrict__ Wvt,
              unsigned short* __restrict__ Wut) {
    __shared__ unsigned short T[64 * 72];
    const int b = blockIdx.x;
    const int t = threadIdx.x;
    const float* src;
    unsigned short* dst;
    int kt, nt, dstld;
    if (b < 64)      { src = W1; dst = W1t; kt = b >> 2;        nt = b & 3;        dstld = 1024; }
    else if (b < 80) { src = Wv; dst = Wvt; kt = (b - 64) >> 2; nt = (b - 64) & 3; dstld = 256; }
    else             { src = Wu; dst = Wut; kt = (b - 80) >> 2; nt = (b - 80) & 3; dstld = 256; }

#pragma unroll
    for (int i = 0; i < 4; ++i) {
        int f = t + i * 256;
        int r = f >> 4, c = (f & 15) * 4;
        float4 v = *(const float4*)(src + (size_t)(kt * 64 + r) * 256 + nt * 64 + c);
        T[(c + 0) * 72 + r] = f2b(v.x);
        T[(c + 1) * 72 + r] = f2b(v.y);
        T[(c + 2) * 72 + r] = f2b(v.z);
        T[(c + 3) * 72 + r] = f2b(v.w);
    }
    __syncthreads();
#pragma unroll
    for (int i = 0; i < 2; ++i) {
        int f = t + i * 256;
        int r = f >> 3, s = (f & 7) * 8;
        *(uint4*)(dst + (size_t)(nt * 64 + r) * dstld + kt * 64 + s) = *(uint4*)&T[r * 72 + s];
    }
}

// ---------------- main fused kernel ----------------
// Stage1: barrier-FREE K-loop. Each wave loads its own A-fragments directly
//   global->VGPR (8 contiguous fp32 per lane = exactly one bf16x8 frag after
//   convert; 4x A re-read served by L1/L2) and B-frags from L2-resident W1t.
//   Depth-2 software pipeline over K=32 steps; no __syncthreads -> loads are
//   never drained, every wave streams independently.
// Stage2: same barrier-free pattern, Hs from LDS as A, Wvt/Wut as B, nc=4
//   column chunks to cap live accumulators (no spills).
__global__ __launch_bounds__(256, 2)
void mil_main(const float* __restrict__ bags,
              const unsigned char* __restrict__ mask,
              const float* __restrict__ b1,
              const float* __restrict__ bv,
              const float* __restrict__ bu,
              const float* __restrict__ ww,
              const float* __restrict__ bwp,
              const unsigned short* __restrict__ W1t,
              const unsigned short* __restrict__ Wvt,
              const unsigned short* __restrict__ Wut,
              float* __restrict__ P) {
    const int tid  = threadIdx.x;
    const int wave = tid >> 6;
    const int lane = tid & 63;
    const int l15  = lane & 15;
    const int quad = lane >> 4;
    const int blk  = blockIdx.x;
    const int row0 = blk * MT;
    const int bag  = blk >> 7;
    const int trow = (blk & 127) * MT;

    __shared__ unsigned short Hs[MT * 264];    // 33792 B
    __shared__ float logits[MT];
    __shared__ float wrow[MT];
    __shared__ float sc[2];

    const float bwv = bwp[0];

    // ---------------- stage 1: h = relu(bags @ W1 + b1), no barriers ----------------
    f32x4 acc[4][4];
#pragma unroll
    for (int mi = 0; mi < 4; ++mi)
#pragma unroll
        for (int ni = 0; ni < 4; ++ni)
            acc[mi][ni] = (f32x4){0.f, 0.f, 0.f, 0.f};

    const float* bagrow = bags + (size_t)row0 * FF;
    const float* aptr[4];
#pragma unroll
    for (int mi = 0; mi < 4; ++mi)
        aptr[mi] = bagrow + (size_t)(mi * 16 + l15) * FF + quad * 8;
    const unsigned short* bptr[4];
#pragma unroll
    for (int ni = 0; ni < 4; ++ni)
        bptr[ni] = W1t + (size_t)(wave * 64 + ni * 16 + l15) * 1024 + quad * 8;

    float4 abuf[2][4][2];
    bf16x8 bbuf[2][4];
    // prologue: steps 0,1 in flight
#pragma unroll
    for (int p = 0; p < 2; ++p) {
#pragma unroll
        for (int mi = 0; mi < 4; ++mi) {
            abuf[p][mi][0] = *(const float4*)(aptr[mi] + p * 32);
            abuf[p][mi][1] = *(const float4*)(aptr[mi] + p * 32 + 4);
        }
#pragma unroll
        for (int ni = 0; ni < 4; ++ni)
            bbuf[p][ni] = *(const bf16x8*)(bptr[ni] + p * 32);
    }

#pragma unroll 4
    for (int s = 0; s < 32; ++s) {
        const int cur = s & 1;
        const int sn = (s + 2 < 32) ? (s + 2) : 31;   // clamped prefetch (dead data at tail)
        // consume A: fp32 -> bf16 fragments
        bf16x8 afr[4];
#pragma unroll
        for (int mi = 0; mi < 4; ++mi) {
            float4 x = abuf[cur][mi][0], y = abuf[cur][mi][1];
            union { bf16x8 v; unsigned u[4]; } t;
            t.u[0] = pk2(x.x, x.y);
            t.u[1] = pk2(x.z, x.w);
            t.u[2] = pk2(y.x, y.y);
            t.u[3] = pk2(y.z, y.w);
            afr[mi] = t.v;
        }
        // re-issue A loads for step s+2 (depth-2 pipeline)
#pragma unroll
        for (int mi = 0; mi < 4; ++mi) {
            abuf[cur][mi][0] = *(const float4*)(aptr[mi] + sn * 32);
            abuf[cur][mi][1] = *(const float4*)(aptr[mi] + sn * 32 + 4);
        }
        // MFMA on this step's A and B
#pragma unroll
        for (int mi = 0; mi < 4; ++mi)
#pragma unroll
            for (int ni = 0; ni < 4; ++ni)
                acc[mi][ni] = __builtin_amdgcn_mfma_f32_16x16x32_bf16(afr[mi], bbuf[cur][ni], acc[mi][ni], 0, 0, 0);
        // re-issue B loads for step s+2
#pragma unroll
        for (int ni = 0; ni < 4; ++ni)
            bbuf[cur][ni] = *(const bf16x8*)(bptr[ni] + sn * 32);
    }

    // Epilogue: +b1, relu, write Hs (bf16). D layout: col=lane&15, row=quad*4+reg.
    {
        float bb[4];
#pragma unroll
        for (int ni = 0; ni < 4; ++ni) bb[ni] = b1[wave * 64 + ni * 16 + l15];
#pragma unroll
        for (int mi = 0; mi < 4; ++mi)
#pragma unroll
            for (int ni = 0; ni < 4; ++ni) {
                int n = wave * 64 + ni * 16 + l15;
#pragma unroll
                for (int r = 0; r < 4; ++r) {
                    int m = mi * 16 + quad * 4 + r;
                    float h = acc[mi][ni][r] + bb[ni];
                    h = fmaxf(h, 0.f);
                    Hs[m * 264 + n] = f2b(h);
                }
            }
    }
    if (tid < MT) logits[tid] = 0.f;
    __syncthreads();   // Hs + logits visible to everyone

    // ---------------- stage 2: gated attention, barrier-free K-loops ----------------
    float rsum[4][4];
#pragma unroll
    for (int mi = 0; mi < 4; ++mi)
#pragma unroll
        for (int r = 0; r < 4; ++r) rsum[mi][r] = 0.f;

#pragma unroll 1
    for (int nc = 0; nc < 4; ++nc) {
        const int n = wave * 64 + nc * 16 + l15;
        const unsigned short* vp = Wvt + (size_t)n * 256 + quad * 8;
        const unsigned short* up = Wut + (size_t)n * 256 + quad * 8;
        f32x4 av[4], au[4];
#pragma unroll
        for (int mi = 0; mi < 4; ++mi) {
            av[mi] = (f32x4){0.f, 0.f, 0.f, 0.f};
            au[mi] = (f32x4){0.f, 0.f, 0.f, 0.f};
        }
#pragma unroll
        for (int ks = 0; ks < 8; ++ks) {
            bf16x8 bvf = *(const bf16x8*)(vp + ks * 32);
            bf16x8 buf = *(const bf16x8*)(up + ks * 32);
            bf16x8 afr[4];
#pragma unroll
            for (int mi = 0; mi < 4; ++mi)
                afr[mi] = *(const bf16x8*)&Hs[(mi * 16 + l15) * 264 + ks * 32 + quad * 8];
#pragma unroll
            for (int mi = 0; mi < 4; ++mi) {
                av[mi] = __builtin_amdgcn_mfma_f32_16x16x32_bf16(afr[mi], bvf, av[mi], 0, 0, 0);
                au[mi] = __builtin_amdgcn_mfma_f32_16x16x32_bf16(afr[mi], buf, au[mi], 0, 0, 0);
            }
        }
        // epilogue: fast tanh * sigmoid * ww -> row partials
        const float bvn = bv[n], bun = bu[n], wn = ww[n];
#pragma unroll
        for (int mi = 0; mi < 4; ++mi)
#pragma unroll
            for (int r = 0; r < 4; ++r) {
                float xv = av[mi][r] + bvn;
                float xu = au[mi][r] + bun;
                float tv = 2.f * __frcp_rn(1.f + __expf(-2.f * xv)) - 1.f;
                float su = __frcp_rn(1.f + __expf(-xu));
                rsum[mi][r] += tv * su * wn;
            }
    }
    // reduce cols within each quad, then cross-wave via LDS atomics
#pragma unroll
    for (int mi = 0; mi < 4; ++mi)
#pragma unroll
        for (int r = 0; r < 4; ++r) {
            float s = rsum[mi][r];
            s += __shfl_xor(s, 1);
            s += __shfl_xor(s, 2);
            s += __shfl_xor(s, 4);
            s += __shfl_xor(s, 8);
            if (l15 == 0) atomicAdd(&logits[mi * 16 + quad * 4 + r], s);
        }
    __syncthreads();

    // finalize logits: + bw, mask
    if (tid < MT) {
        float lg = logits[tid] + bwv;
        if (mask[bag * TT + trow + tid]) lg = -INFINITY;
        logits[tid] = lg;
    }
    __syncthreads();

    // block-local softmax stats (wave 0)
    if (wave == 0) {
        float v = logits[lane];
        float mx = v;
#pragma unroll
        for (int off = 1; off < 64; off <<= 1) mx = fmaxf(mx, __shfl_xor(mx, off));
        float w = (mx == -INFINITY) ? 0.f : __expf(v - mx);
        wrow[lane] = w;
        float l = w;
#pragma unroll
        for (int off = 1; off < 64; off <<= 1) l += __shfl_xor(l, off);
        if (lane == 0) { sc[0] = mx; sc[1] = l; }
    }
    __syncthreads();

    // weighted aggregation: acc[n] = sum_m w[m] * h[m][n]
    float a = 0.f;
#pragma unroll 8
    for (int m = 0; m < MT; ++m)
        a += wrow[m] * b2f(Hs[m * 264 + tid]);

    float* rec = P + (size_t)blk * PSTR;
    rec[2 + tid] = a;
    if (tid == 0) { rec[0] = sc[0]; rec[1] = sc[1]; }
}

// ---------------- final: per-bag reduction + classifier ----------------
__global__ void mil_final(const float* __restrict__ P,
                          const float* __restrict__ Wc,
                          const float* __restrict__ bc,
                          float* __restrict__ out) {
    const int bag = blockIdx.x;
    const int tid = threadIdx.x;
    __shared__ float marr[PBAG];
    __shared__ float earr[PBAG];
    __shared__ float red[4];
    __shared__ float wred[8];

    if (tid < PBAG) marr[tid] = P[(size_t)(bag * PBAG + tid) * PSTR + 0];
    __syncthreads();
    if (tid < PBAG) {
        float v = marr[tid];
#pragma unroll
        for (int off = 1; off < 64; off <<= 1) v = fmaxf(v, __shfl_xor(v, off));
        if ((tid & 63) == 0) red[tid >> 6] = v;
    }
    __syncthreads();
    const float M = fmaxf(red[0], red[1]);
    if (tid < PBAG) {
        float e = (marr[tid] == -INFINITY) ? 0.f : __expf(marr[tid] - M);
        earr[tid] = e;
        float le = P[(size_t)(bag * PBAG + tid) * PSTR + 1] * e;
#pragma unroll
        for (int off = 1; off < 64; off <<= 1) le += __shfl_xor(le, off);
        if ((tid & 63) == 0) red[2 + (tid >> 6)] = le;
    }
    __syncthreads();
    const float L = red[2] + red[3];

    float accv = 0.f;
#pragma unroll 4
    for (int i = 0; i < PBAG; ++i)
        accv += earr[i] * P[(size_t)(bag * PBAG + i) * PSTR + 2 + tid];
    const float sr = accv / L;

    float p0 = sr * Wc[tid * 2 + 0];
    float p1 = sr * Wc[tid * 2 + 1];
#pragma unroll
    for (int off = 1; off < 64; off <<= 1) {
        p0 += __shfl_xor(p0, off);
        p1 += __shfl_xor(p1, off);
    }
    if ((tid & 63) == 0) {
        wred[(tid >> 6) * 2 + 0] = p0;
        wred[(tid >> 6) * 2 + 1] = p1;
    }
    __syncthreads();
    if (tid == 0) {
        out[bag * 2 + 0] = wred[0] + wred[2] + wred[4] + wred[6] + bc[0];
        out[bag * 2 + 1] = wred[1] + wred[3] + wred[5] + wred[7] + bc[1];
    }
}

extern "C" void kernel_launch(void* const* d_in, const int* in_sizes, int n_in,
                              void* d_out, int out_size, void* d_ws, size_t ws_size,
                              hipStream_t stream) {
    const float*         bags = (const float*)d_in[0];
    const unsigned char* mask = (const unsigned char*)d_in[1];
    const float*         W1   = (const float*)d_in[2];
    const float*         b1   = (const float*)d_in[3];
    const float*         Wv   = (const float*)d_in[4];
    const float*         bv   = (const float*)d_in[5];
    const float*         Wu   = (const float*)d_in[6];
    const float*         bu   = (const float*)d_in[7];
    const float*         ww   = (const float*)d_in[8];
    const float*         bw   = (const float*)d_in[9];
    const float*         Wc   = (const float*)d_in[10];
    const float*         bc   = (const float*)d_in[11];
    float* out = (float*)d_out;

    char* ws = (char*)d_ws;
    unsigned short* W1t = (unsigned short*)(ws);                    // 524288 B
    unsigned short* Wvt = (unsigned short*)(ws + 524288);           // 131072 B
    unsigned short* Wut = (unsigned short*)(ws + 655360);           // 131072 B
    float*          P   = (float*)(ws + 786432);                    // 1024*260*4 B

    mil_prep<<<96, 256, 0, stream>>>(W1, Wv, Wu, W1t, Wvt, Wut);
    mil_main<<<NBLK, 256, 0, stream>>>(bags, mask, b1, bv, bu, ww, bw, W1t, Wvt, Wut, P);
    mil_final<<<BB, 256, 0, stream>>>(P, Wc, bc, out);
}

// Round 4
// 475.382 us; speedup vs baseline: 1.1493x; 1.1493x over previous
//
#include <hip/hip_runtime.h>
#include <math.h>

// Problem constants
#define BB 8
#define TT 8192
#define FF 1024
#define HH 256
#define MT 64               // rows per block
#define NBLK ((BB*TT)/MT)   // 1024 main blocks
#define PBAG (TT/MT)        // 128 blocks per bag
#define PSTR 260            // floats per partial record: [m, l, acc[256], pad2]

typedef __attribute__((ext_vector_type(8))) short bf16x8;
typedef __attribute__((ext_vector_type(4))) float f32x4;

__device__ __forceinline__ float b2f(unsigned short s) {
    union { unsigned u; float f; } v; v.u = ((unsigned)s) << 16; return v.f;
}
__device__ __forceinline__ unsigned short f2b(float f) {
    union { float f; unsigned u; } v; v.f = f;
    unsigned u = v.u;
    return (unsigned short)((u + 0x7fffu + ((u >> 16) & 1u)) >> 16);
}
__device__ __forceinline__ unsigned pk2(float a, float b) {
    return (unsigned)f2b(a) | ((unsigned)f2b(b) << 16);
}

// ---------------- prep: emit weights in MFMA B-fragment order ----------------
// W1f frag addr: (((w*16+kb)*2+k0i)*4+ni)*512 + lane*8 + j
//   holds W1[k][n], n = w*64+ni*16+(lane&15), k = kb*64+k0i*32+(lane>>4)*8+j
// Wvf/Wuf frag addr: ((w*4+nc)*8+ks)*512 + lane*8 + j
//   holds Wv[k][n], n = w*64+nc*16+(lane&15), k = ks*32+(lane>>4)*8+j
// => every kernel B-frag load is one lane-contiguous 1KB dwordx4.
__global__ __launch_bounds__(256)
void mil_prep(const float* __restrict__ W1,
              const float* __restrict__ Wv,
              const float* __restrict__ Wu,
              unsigned short* __restrict__ W1f,
              unsigned short* __restrict__ Wvf,
              unsigned short* __restrict__ Wuf) {
    __shared__ unsigned short T[64 * 264];   // transposed bf16 tile T[n_local][k]
    const int b = blockIdx.x;
    const int t = threadIdx.x;
    if (b < 64) {
        const int w = b >> 4, kb = b & 15;
        // read 64(k) x 64(n) fp32 tile, store T[n_local][k_local] stride 72
#pragma unroll
        for (int i = 0; i < 4; ++i) {
            int f = t + i * 256;
            int r = f >> 4, c4 = (f & 15) * 4;   // r=k_local, c4=n_local
            float4 v = *(const float4*)(W1 + (size_t)(kb * 64 + r) * 256 + w * 64 + c4);
            T[(c4 + 0) * 72 + r] = f2b(v.x);
            T[(c4 + 1) * 72 + r] = f2b(v.y);
            T[(c4 + 2) * 72 + r] = f2b(v.z);
            T[(c4 + 3) * 72 + r] = f2b(v.w);
        }
        __syncthreads();
#pragma unroll
        for (int i = 0; i < 2; ++i) {
            int c = t + i * 256;                 // 512 16B-chunks
            int fl = c >> 6;                     // k0i*4+ni
            int k0i = fl >> 2, ni = fl & 3;
            int lane = c & 63, l15 = lane & 15, q = lane >> 4;
            *(uint4*)(W1f + ((size_t)(w * 16 + kb) * 8 + fl) * 512 + lane * 8) =
                *(const uint4*)&T[(ni * 16 + l15) * 72 + k0i * 32 + q * 8];
        }
    } else {
        const int m = (b - 64) >> 2;             // 0=Wv, 1=Wu
        const int w = (b - 64) & 3;
        const float* src = m ? Wu : Wv;
        unsigned short* dst = m ? Wuf : Wvf;
        // read 256(k) x 64(n) fp32, store T[n_local][k] stride 264
#pragma unroll
        for (int i = 0; i < 16; ++i) {
            int f = t + i * 256;
            int r = f >> 4, c4 = (f & 15) * 4;
            float4 v = *(const float4*)(src + (size_t)r * 256 + w * 64 + c4);
            T[(c4 + 0) * 264 + r] = f2b(v.x);
            T[(c4 + 1) * 264 + r] = f2b(v.y);
            T[(c4 + 2) * 264 + r] = f2b(v.z);
            T[(c4 + 3) * 264 + r] = f2b(v.w);
        }
        __syncthreads();
#pragma unroll
        for (int i = 0; i < 8; ++i) {
            int c = t + i * 256;                 // 2048 16B-chunks
            int fl = c >> 6;                     // nc*8+ks
            int nc = fl >> 3, ks = fl & 7;
            int lane = c & 63, l15 = lane & 15, q = lane >> 4;
            *(uint4*)(dst + ((size_t)(w * 4 + nc) * 8 + ks) * 512 + lane * 8) =
                *(const uint4*)&T[(nc * 16 + l15) * 264 + ks * 32 + q * 8];
        }
    }
}

// ---------------- stage 1: h = relu(bags @ W1 + b1) -> Hg (bf16) ----------------
// Double-buffered As, ONE barrier per chunk with zero outstanding vmem at the
// barrier (drain is free). B-frags are coalesced 1KB loads from L2-resident W1f,
// issued before the bags prefetch so their wait doesn't drain it.
__global__ __launch_bounds__(256, 3)
void mil_stage1(const float* __restrict__ bags,
                const float* __restrict__ b1,
                const unsigned short* __restrict__ W1f,
                unsigned short* __restrict__ Hg) {
    const int tid  = threadIdx.x;
    const int wave = tid >> 6;
    const int lane = tid & 63;
    const int l15  = lane & 15;
    const int quad = lane >> 4;
    const int blk  = blockIdx.x;

    __shared__ unsigned short U[64 * 264];     // 33792 B; As dbuf aliases front
    unsigned short* As = U;                    // [2][64*72] = 9216 shorts

    f32x4 acc[4][4];
#pragma unroll
    for (int mi = 0; mi < 4; ++mi)
#pragma unroll
        for (int ni = 0; ni < 4; ++ni)
            acc[mi][ni] = (f32x4){0.f, 0.f, 0.f, 0.f};

    const float* bagrow = bags + (size_t)blk * MT * FF;
    int fr[4], fc[4];
    float4 pf[4];
#pragma unroll
    for (int i = 0; i < 4; ++i) {
        int f = tid + i * 256;
        fr[i] = f >> 4;
        fc[i] = (f & 15) * 4;
        pf[i] = *(const float4*)(bagrow + (size_t)fr[i] * FF + fc[i]);
    }
    const unsigned short* bs = W1f + (size_t)wave * 16 * 4096;  // this wave's B stream

#pragma unroll 2
    for (int kb = 0; kb < 16; ++kb) {
        const int buf = (kb & 1) * 4608;       // 64*72
        // store staged chunk kb (compiler waits vmcnt for pf here)
#pragma unroll
        for (int i = 0; i < 4; ++i)
            *(uint2*)&As[buf + fr[i] * 72 + fc[i]] =
                make_uint2(pk2(pf[i].x, pf[i].y), pk2(pf[i].z, pf[i].w));
        __syncthreads();                        // nothing outstanding: free drain
        // B-frags for kb (issue FIRST so MFMA's wait leaves pf in flight)
        bf16x8 bb[8];
#pragma unroll
        for (int f8 = 0; f8 < 8; ++f8)
            bb[f8] = *(const bf16x8*)(bs + kb * 4096 + f8 * 512 + lane * 8);
        // prefetch chunk kb+1 (HBM; hidden across MFMA section)
        if (kb < 15) {
#pragma unroll
            for (int i = 0; i < 4; ++i)
                pf[i] = *(const float4*)(bagrow + (size_t)fr[i] * FF + (kb + 1) * 64 + fc[i]);
        }
#pragma unroll
        for (int k0i = 0; k0i < 2; ++k0i) {
            bf16x8 afr[4];
#pragma unroll
            for (int mi = 0; mi < 4; ++mi)
                afr[mi] = *(const bf16x8*)&As[buf + (mi * 16 + l15) * 72 + k0i * 32 + quad * 8];
#pragma unroll
            for (int mi = 0; mi < 4; ++mi)
#pragma unroll
                for (int ni = 0; ni < 4; ++ni)
                    acc[mi][ni] = __builtin_amdgcn_mfma_f32_16x16x32_bf16(afr[mi], bb[k0i * 4 + ni], acc[mi][ni], 0, 0, 0);
        }
    }
    __syncthreads();   // all As reads done; reuse U as Ht[64][264]

    {
        float bbv[4];
#pragma unroll
        for (int ni = 0; ni < 4; ++ni) bbv[ni] = b1[wave * 64 + ni * 16 + l15];
#pragma unroll
        for (int mi = 0; mi < 4; ++mi)
#pragma unroll
            for (int ni = 0; ni < 4; ++ni) {
                int n = wave * 64 + ni * 16 + l15;
#pragma unroll
                for (int r = 0; r < 4; ++r) {
                    int m = mi * 16 + quad * 4 + r;
                    float h = fmaxf(acc[mi][ni][r] + bbv[ni], 0.f);
                    U[m * 264 + n] = f2b(h);
                }
            }
    }
    __syncthreads();
    // coalesced copy Ht -> Hg[blk][64][256]
#pragma unroll
    for (int i = 0; i < 8; ++i) {
        int f = tid + i * 256;
        int r = f >> 5, c8 = (f & 31) * 8;
        *(uint4*)(Hg + (size_t)blk * 16384 + r * 256 + c8) = *(const uint4*)&U[r * 264 + c8];
    }
}

// ---------------- stage 2: gated attention + block softmax partials ----------------
__global__ __launch_bounds__(256, 4)
void mil_stage2(const unsigned short* __restrict__ Hg,
                const unsigned char* __restrict__ mask,
                const float* __restrict__ bv,
                const float* __restrict__ bu,
                const float* __restrict__ ww,
                const float* __restrict__ bwp,
                const unsigned short* __restrict__ Wvf,
                const unsigned short* __restrict__ Wuf,
                float* __restrict__ P) {
    const int tid  = threadIdx.x;
    const int wave = tid >> 6;
    const int lane = tid & 63;
    const int l15  = lane & 15;
    const int quad = lane >> 4;
    const int blk  = blockIdx.x;
    const int bag  = blk >> 7;
    const int trow = (blk & 127) * MT;

    __shared__ unsigned short Hs[MT * 264];    // 33792 B
    __shared__ float logits[MT];
    __shared__ float wrow[MT];
    __shared__ float sc[2];

    // stage h tile (coalesced 16B loads -> padded LDS)
#pragma unroll
    for (int i = 0; i < 8; ++i) {
        int f = tid + i * 256;
        int r = f >> 5, c8 = (f & 31) * 8;
        *(uint4*)&Hs[r * 264 + c8] = *(const uint4*)(Hg + (size_t)blk * 16384 + r * 256 + c8);
    }
    if (tid < MT) logits[tid] = 0.f;
    __syncthreads();

    float rsum[4][4];
#pragma unroll
    for (int mi = 0; mi < 4; ++mi)
#pragma unroll
        for (int r = 0; r < 4; ++r) rsum[mi][r] = 0.f;

#pragma unroll 1
    for (int nc = 0; nc < 4; ++nc) {
        const int n = wave * 64 + nc * 16 + l15;
        const unsigned short* vs = Wvf + ((size_t)(wave * 4 + nc) * 8) * 512;
        const unsigned short* us = Wuf + ((size_t)(wave * 4 + nc) * 8) * 512;
        f32x4 av[4], au[4];
#pragma unroll
        for (int mi = 0; mi < 4; ++mi) {
            av[mi] = (f32x4){0.f, 0.f, 0.f, 0.f};
            au[mi] = (f32x4){0.f, 0.f, 0.f, 0.f};
        }
#pragma unroll 2
        for (int ks = 0; ks < 8; ++ks) {
            bf16x8 bvf = *(const bf16x8*)(vs + ks * 512 + lane * 8);
            bf16x8 buf_ = *(const bf16x8*)(us + ks * 512 + lane * 8);
            bf16x8 afr[4];
#pragma unroll
            for (int mi = 0; mi < 4; ++mi)
                afr[mi] = *(const bf16x8*)&Hs[(mi * 16 + l15) * 264 + ks * 32 + quad * 8];
#pragma unroll
            for (int mi = 0; mi < 4; ++mi) {
                av[mi] = __builtin_amdgcn_mfma_f32_16x16x32_bf16(afr[mi], bvf, av[mi], 0, 0, 0);
                au[mi] = __builtin_amdgcn_mfma_f32_16x16x32_bf16(afr[mi], buf_, au[mi], 0, 0, 0);
            }
        }
        const float bvn = bv[n], bun = bu[n], wn = ww[n];
#pragma unroll
        for (int mi = 0; mi < 4; ++mi)
#pragma unroll
            for (int r = 0; r < 4; ++r) {
                float xv = av[mi][r] + bvn;
                float xu = au[mi][r] + bun;
                float tv = 2.f * __frcp_rn(1.f + __expf(-2.f * xv)) - 1.f;
                float su = __frcp_rn(1.f + __expf(-xu));
                rsum[mi][r] += tv * su * wn;
            }
    }
#pragma unroll
    for (int mi = 0; mi < 4; ++mi)
#pragma unroll
        for (int r = 0; r < 4; ++r) {
            float s = rsum[mi][r];
            s += __shfl_xor(s, 1);
            s += __shfl_xor(s, 2);
            s += __shfl_xor(s, 4);
            s += __shfl_xor(s, 8);
            if (l15 == 0) atomicAdd(&logits[mi * 16 + quad * 4 + r], s);
        }
    __syncthreads();

    if (tid < MT) {
        float lg = logits[tid] + bwp[0];
        if (mask[bag * TT + trow + tid]) lg = -INFINITY;
        logits[tid] = lg;
    }
    __syncthreads();

    if (wave == 0) {
        float v = logits[lane];
        float mx = v;
#pragma unroll
        for (int off = 1; off < 64; off <<= 1) mx = fmaxf(mx, __shfl_xor(mx, off));
        float w = (mx == -INFINITY) ? 0.f : __expf(v - mx);
        wrow[lane] = w;
        float l = w;
#pragma unroll
        for (int off = 1; off < 64; off <<= 1) l += __shfl_xor(l, off);
        if (lane == 0) { sc[0] = mx; sc[1] = l; }
    }
    __syncthreads();

    float a = 0.f;
#pragma unroll 8
    for (int m = 0; m < MT; ++m)
        a += wrow[m] * b2f(Hs[m * 264 + tid]);

    float* rec = P + (size_t)blk * PSTR;
    rec[2 + tid] = a;
    if (tid == 0) { rec[0] = sc[0]; rec[1] = sc[1]; }
}

// ---------------- final: per-bag reduction + classifier ----------------
__global__ void mil_final(const float* __restrict__ P,
                          const float* __restrict__ Wc,
                          const float* __restrict__ bc,
                          float* __restrict__ out) {
    const int bag = blockIdx.x;
    const int tid = threadIdx.x;
    __shared__ float marr[PBAG];
    __shared__ float earr[PBAG];
    __shared__ float red[4];
    __shared__ float wred[8];

    if (tid < PBAG) marr[tid] = P[(size_t)(bag * PBAG + tid) * PSTR + 0];
    __syncthreads();
    if (tid < PBAG) {
        float v = marr[tid];
#pragma unroll
        for (int off = 1; off < 64; off <<= 1) v = fmaxf(v, __shfl_xor(v, off));
        if ((tid & 63) == 0) red[tid >> 6] = v;
    }
    __syncthreads();
    const float M = fmaxf(red[0], red[1]);
    if (tid < PBAG) {
        float e = (marr[tid] == -INFINITY) ? 0.f : __expf(marr[tid] - M);
        earr[tid] = e;
        float le = P[(size_t)(bag * PBAG + tid) * PSTR + 1] * e;
#pragma unroll
        for (int off = 1; off < 64; off <<= 1) le += __shfl_xor(le, off);
        if ((tid & 63) == 0) red[2 + (tid >> 6)] = le;
    }
    __syncthreads();
    const float L = red[2] + red[3];

    float accv = 0.f;
#pragma unroll 4
    for (int i = 0; i < PBAG; ++i)
        accv += earr[i] * P[(size_t)(bag * PBAG + i) * PSTR + 2 + tid];
    const float sr = accv / L;

    float p0 = sr * Wc[tid * 2 + 0];
    float p1 = sr * Wc[tid * 2 + 1];
#pragma unroll
    for (int off = 1; off < 64; off <<= 1) {
        p0 += __shfl_xor(p0, off);
        p1 += __shfl_xor(p1, off);
    }
    if ((tid & 63) == 0) {
        wred[(tid >> 6) * 2 + 0] = p0;
        wred[(tid >> 6) * 2 + 1] = p1;
    }
    __syncthreads();
    if (tid == 0) {
        out[bag * 2 + 0] = wred[0] + wred[2] + wred[4] + wred[6] + bc[0];
        out[bag * 2 + 1] = wred[1] + wred[3] + wred[5] + wred[7] + bc[1];
    }
}

extern "C" void kernel_launch(void* const* d_in, const int* in_sizes, int n_in,
                              void* d_out, int out_size, void* d_ws, size_t ws_size,
                              hipStream_t stream) {
    const float*         bags = (const float*)d_in[0];
    const unsigned char* mask = (const unsigned char*)d_in[1];
    const float*         W1   = (const float*)d_in[2];
    const float*         b1   = (const float*)d_in[3];
    const float*         bv   = (const float*)d_in[5];
    const float*         Wv   = (const float*)d_in[4];
    const float*         Wu   = (const float*)d_in[6];
    const float*         bu   = (const float*)d_in[7];
    const float*         ww   = (const float*)d_in[8];
    const float*         bw   = (const float*)d_in[9];
    const float*         Wc   = (const float*)d_in[10];
    const float*         bc   = (const float*)d_in[11];
    float* out = (float*)d_out;

    char* ws = (char*)d_ws;
    unsigned short* W1f = (unsigned short*)(ws);                    // 524288 B
    unsigned short* Wvf = (unsigned short*)(ws + 524288);           // 131072 B
    unsigned short* Wuf = (unsigned short*)(ws + 655360);           // 131072 B
    float*          P   = (float*)(ws + 786432);                    // 1064960 B
    unsigned short* Hg  = (unsigned short*)(ws + 1851392);          // 33554432 B

    mil_prep<<<72, 256, 0, stream>>>(W1, Wv, Wu, W1f, Wvf, Wuf);
    mil_stage1<<<NBLK, 256, 0, stream>>>(bags, b1, W1f, Hg);
    mil_stage2<<<NBLK, 256, 0, stream>>>(Hg, mask, bv, bu, ww, bw, Wvf, Wuf, P);
    mil_final<<<BB, 256, 0, stream>>>(P, Wc, bc, out);
}

// Round 5
// 441.827 us; speedup vs baseline: 1.2366x; 1.0759x over previous
//
#include <hip/hip_runtime.h>
#include <math.h>

// Problem constants
#define BB 8
#define TT 8192
#define FF 1024
#define HH 256
#define MT 64               // rows per block
#define NBLK ((BB*TT)/MT)   // 1024 main blocks
#define PBAG (TT/MT)        // 128 blocks per bag
#define PSTR 260            // floats per partial record: [m, l, acc[256], pad2]

typedef __attribute__((ext_vector_type(8))) short bf16x8;
typedef __attribute__((ext_vector_type(4))) float f32x4;

__device__ __forceinline__ float b2f(unsigned short s) {
    union { unsigned u; float f; } v; v.u = ((unsigned)s) << 16; return v.f;
}
__device__ __forceinline__ unsigned short f2b(float f) {
    union { float f; unsigned u; } v; v.f = f;
    unsigned u = v.u;
    return (unsigned short)((u + 0x7fffu + ((u >> 16) & 1u)) >> 16);
}
__device__ __forceinline__ unsigned pk2(float a, float b) {
    return (unsigned)f2b(a) | ((unsigned)f2b(b) << 16);
}

// ---------------- prep: emit weights in MFMA B-fragment order ----------------
// W1f frag addr: (((w*16+kb)*2+k0i)*4+ni)*512 + lane*8 + j
//   holds W1[k][n], n = w*64+ni*16+(lane&15), k = kb*64+k0i*32+(lane>>4)*8+j
// Wvf/Wuf frag addr: ((w*4+nc)*8+ks)*512 + lane*8 + j
__global__ __launch_bounds__(256)
void mil_prep(const float* __restrict__ W1,
              const float* __restrict__ Wv,
              const float* __restrict__ Wu,
              unsigned short* __restrict__ W1f,
              unsigned short* __restrict__ Wvf,
              unsigned short* __restrict__ Wuf) {
    __shared__ unsigned short T[64 * 264];
    const int b = blockIdx.x;
    const int t = threadIdx.x;
    if (b < 64) {
        const int w = b >> 4, kb = b & 15;
#pragma unroll
        for (int i = 0; i < 4; ++i) {
            int f = t + i * 256;
            int r = f >> 4, c4 = (f & 15) * 4;
            float4 v = *(const float4*)(W1 + (size_t)(kb * 64 + r) * 256 + w * 64 + c4);
            T[(c4 + 0) * 72 + r] = f2b(v.x);
            T[(c4 + 1) * 72 + r] = f2b(v.y);
            T[(c4 + 2) * 72 + r] = f2b(v.z);
            T[(c4 + 3) * 72 + r] = f2b(v.w);
        }
        __syncthreads();
#pragma unroll
        for (int i = 0; i < 2; ++i) {
            int c = t + i * 256;
            int fl = c >> 6;
            int k0i = fl >> 2, ni = fl & 3;
            int lane = c & 63, l15 = lane & 15, q = lane >> 4;
            *(uint4*)(W1f + ((size_t)(w * 16 + kb) * 8 + fl) * 512 + lane * 8) =
                *(const uint4*)&T[(ni * 16 + l15) * 72 + k0i * 32 + q * 8];
        }
    } else {
        const int m = (b - 64) >> 2;
        const int w = (b - 64) & 3;
        const float* src = m ? Wu : Wv;
        unsigned short* dst = m ? Wuf : Wvf;
#pragma unroll
        for (int i = 0; i < 16; ++i) {
            int f = t + i * 256;
            int r = f >> 4, c4 = (f & 15) * 4;
            float4 v = *(const float4*)(src + (size_t)r * 256 + w * 64 + c4);
            T[(c4 + 0) * 264 + r] = f2b(v.x);
            T[(c4 + 1) * 264 + r] = f2b(v.y);
            T[(c4 + 2) * 264 + r] = f2b(v.z);
            T[(c4 + 3) * 264 + r] = f2b(v.w);
        }
        __syncthreads();
#pragma unroll
        for (int i = 0; i < 8; ++i) {
            int c = t + i * 256;
            int fl = c >> 6;
            int nc = fl >> 3, ks = fl & 7;
            int lane = c & 63, l15 = lane & 15, q = lane >> 4;
            *(uint4*)(dst + ((size_t)(w * 4 + nc) * 8 + ks) * 512 + lane * 8) =
                *(const uint4*)&T[(nc * 16 + l15) * 264 + ks * 32 + q * 8];
        }
    }
}

// ---------------- stage 1: h = relu(bags @ W1 + b1) -> Hg (bf16) ----------------
// BK=128 chunks (8 iters): 8 float4/thread in flight (128B/lane), MFMA section
// ~= HBM latency, one free-drain barrier per chunk. As double-buffered (stride
// 136 = 2-way bank alias, free). B-frags (L2) issued BEFORE the bags prefetch
// so the MFMA vmcnt wait leaves pf in flight. 2 blocks/CU, ~200 VGPR, no spill.
__global__ __launch_bounds__(256, 2)
void mil_stage1(const float* __restrict__ bags,
                const float* __restrict__ b1,
                const unsigned short* __restrict__ W1f,
                unsigned short* __restrict__ Hg) {
    const int tid  = threadIdx.x;
    const int wave = tid >> 6;
    const int lane = tid & 63;
    const int l15  = lane & 15;
    const int quad = lane >> 4;
    const int blk  = blockIdx.x;

    __shared__ unsigned short LB[2 * 64 * 136];   // 34816 B; Ht (64x264) aliases

    f32x4 acc[4][4];
#pragma unroll
    for (int mi = 0; mi < 4; ++mi)
#pragma unroll
        for (int ni = 0; ni < 4; ++ni)
            acc[mi][ni] = (f32x4){0.f, 0.f, 0.f, 0.f};

    const float* bagrow = bags + (size_t)blk * MT * FF;
    int fr[8], fc[8];
    float4 pf[8];
#pragma unroll
    for (int i = 0; i < 8; ++i) {
        int f = tid + i * 256;
        fr[i] = f >> 5;
        fc[i] = (f & 31) * 4;
        pf[i] = *(const float4*)(bagrow + (size_t)fr[i] * FF + fc[i]);
    }
    const unsigned short* bs = W1f + (size_t)wave * 16 * 4096;

#pragma unroll 2
    for (int kb2 = 0; kb2 < 8; ++kb2) {
        unsigned short* A = LB + (kb2 & 1) * 8704;   // 64*136
        // store staged chunk (waits pf: issued one full iteration ago)
#pragma unroll
        for (int i = 0; i < 8; ++i)
            *(uint2*)&A[fr[i] * 136 + fc[i]] =
                make_uint2(pk2(pf[i].x, pf[i].y), pk2(pf[i].z, pf[i].w));
        __syncthreads();                              // nothing outstanding: free drain
        // B-frags for both 64-K halves (issue FIRST -> MFMA wait = vmcnt(8), pf alive)
        bf16x8 bb[16];
#pragma unroll
        for (int f16 = 0; f16 < 16; ++f16)
            bb[f16] = *(const bf16x8*)(bs + (size_t)(kb2 * 2 + (f16 >> 3)) * 4096
                                       + (f16 & 7) * 512 + lane * 8);
        // prefetch next 128-K chunk of bags (in flight across the MFMA section)
        if (kb2 < 7) {
#pragma unroll
            for (int i = 0; i < 8; ++i)
                pf[i] = *(const float4*)(bagrow + (size_t)fr[i] * FF + (kb2 + 1) * 128 + fc[i]);
        }
#pragma unroll
        for (int k0i = 0; k0i < 4; ++k0i) {
            bf16x8 afr[4];
#pragma unroll
            for (int mi = 0; mi < 4; ++mi)
                afr[mi] = *(const bf16x8*)&A[(mi * 16 + l15) * 136 + k0i * 32 + quad * 8];
#pragma unroll
            for (int mi = 0; mi < 4; ++mi)
#pragma unroll
                for (int ni = 0; ni < 4; ++ni)
                    acc[mi][ni] = __builtin_amdgcn_mfma_f32_16x16x32_bf16(afr[mi], bb[k0i * 4 + ni], acc[mi][ni], 0, 0, 0);
        }
    }
    __syncthreads();   // all As reads done; reuse LB as Ht[64][264]

    {
        float bbv[4];
#pragma unroll
        for (int ni = 0; ni < 4; ++ni) bbv[ni] = b1[wave * 64 + ni * 16 + l15];
#pragma unroll
        for (int mi = 0; mi < 4; ++mi)
#pragma unroll
            for (int ni = 0; ni < 4; ++ni) {
                int n = wave * 64 + ni * 16 + l15;
#pragma unroll
                for (int r = 0; r < 4; ++r) {
                    int m = mi * 16 + quad * 4 + r;
                    float h = fmaxf(acc[mi][ni][r] + bbv[ni], 0.f);
                    LB[m * 264 + n] = f2b(h);
                }
            }
    }
    __syncthreads();
    // coalesced copy Ht -> Hg[blk][64][256]
#pragma unroll
    for (int i = 0; i < 8; ++i) {
        int f = tid + i * 256;
        int r = f >> 5, c8 = (f & 31) * 8;
        *(uint4*)(Hg + (size_t)blk * 16384 + r * 256 + c8) = *(const uint4*)&LB[r * 264 + c8];
    }
}

// ---------------- stage 2: gated attention + block softmax partials ----------------
__global__ __launch_bounds__(256, 4)
void mil_stage2(const unsigned short* __restrict__ Hg,
                const unsigned char* __restrict__ mask,
                const float* __restrict__ bv,
                const float* __restrict__ bu,
                const float* __restrict__ ww,
                const float* __restrict__ bwp,
                const unsigned short* __restrict__ Wvf,
                const unsigned short* __restrict__ Wuf,
                float* __restrict__ P) {
    const int tid  = threadIdx.x;
    const int wave = tid >> 6;
    const int lane = tid & 63;
    const int l15  = lane & 15;
    const int quad = lane >> 4;
    const int blk  = blockIdx.x;
    const int bag  = blk >> 7;
    const int trow = (blk & 127) * MT;

    __shared__ unsigned short Hs[MT * 264];
    __shared__ float logits[MT];
    __shared__ float wrow[MT];
    __shared__ float sc[2];

#pragma unroll
    for (int i = 0; i < 8; ++i) {
        int f = tid + i * 256;
        int r = f >> 5, c8 = (f & 31) * 8;
        *(uint4*)&Hs[r * 264 + c8] = *(const uint4*)(Hg + (size_t)blk * 16384 + r * 256 + c8);
    }
    if (tid < MT) logits[tid] = 0.f;
    __syncthreads();

    float rsum[4][4];
#pragma unroll
    for (int mi = 0; mi < 4; ++mi)
#pragma unroll
        for (int r = 0; r < 4; ++r) rsum[mi][r] = 0.f;

#pragma unroll 1
    for (int nc = 0; nc < 4; ++nc) {
        const int n = wave * 64 + nc * 16 + l15;
        const unsigned short* vs = Wvf + ((size_t)(wave * 4 + nc) * 8) * 512;
        const unsigned short* us = Wuf + ((size_t)(wave * 4 + nc) * 8) * 512;
        f32x4 av[4], au[4];
#pragma unroll
        for (int mi = 0; mi < 4; ++mi) {
            av[mi] = (f32x4){0.f, 0.f, 0.f, 0.f};
            au[mi] = (f32x4){0.f, 0.f, 0.f, 0.f};
        }
#pragma unroll 2
        for (int ks = 0; ks < 8; ++ks) {
            bf16x8 bvf = *(const bf16x8*)(vs + ks * 512 + lane * 8);
            bf16x8 buf_ = *(const bf16x8*)(us + ks * 512 + lane * 8);
            bf16x8 afr[4];
#pragma unroll
            for (int mi = 0; mi < 4; ++mi)
                afr[mi] = *(const bf16x8*)&Hs[(mi * 16 + l15) * 264 + ks * 32 + quad * 8];
#pragma unroll
            for (int mi = 0; mi < 4; ++mi) {
                av[mi] = __builtin_amdgcn_mfma_f32_16x16x32_bf16(afr[mi], bvf, av[mi], 0, 0, 0);
                au[mi] = __builtin_amdgcn_mfma_f32_16x16x32_bf16(afr[mi], buf_, au[mi], 0, 0, 0);
            }
        }
        const float bvn = bv[n], bun = bu[n], wn = ww[n];
#pragma unroll
        for (int mi = 0; mi < 4; ++mi)
#pragma unroll
            for (int r = 0; r < 4; ++r) {
                float xv = av[mi][r] + bvn;
                float xu = au[mi][r] + bun;
                float tv = 2.f * __frcp_rn(1.f + __expf(-2.f * xv)) - 1.f;
                float su = __frcp_rn(1.f + __expf(-xu));
                rsum[mi][r] += tv * su * wn;
            }
    }
#pragma unroll
    for (int mi = 0; mi < 4; ++mi)
#pragma unroll
        for (int r = 0; r < 4; ++r) {
            float s = rsum[mi][r];
            s += __shfl_xor(s, 1);
            s += __shfl_xor(s, 2);
            s += __shfl_xor(s, 4);
            s += __shfl_xor(s, 8);
            if (l15 == 0) atomicAdd(&logits[mi * 16 + quad * 4 + r], s);
        }
    __syncthreads();

    if (tid < MT) {
        float lg = logits[tid] + bwp[0];
        if (mask[bag * TT + trow + tid]) lg = -INFINITY;
        logits[tid] = lg;
    }
    __syncthreads();

    if (wave == 0) {
        float v = logits[lane];
        float mx = v;
#pragma unroll
        for (int off = 1; off < 64; off <<= 1) mx = fmaxf(mx, __shfl_xor(mx, off));
        float w = (mx == -INFINITY) ? 0.f : __expf(v - mx);
        wrow[lane] = w;
        float l = w;
#pragma unroll
        for (int off = 1; off < 64; off <<= 1) l += __shfl_xor(l, off);
        if (lane == 0) { sc[0] = mx; sc[1] = l; }
    }
    __syncthreads();

    float a = 0.f;
#pragma unroll 8
    for (int m = 0; m < MT; ++m)
        a += wrow[m] * b2f(Hs[m * 264 + tid]);

    float* rec = P + (size_t)blk * PSTR;
    rec[2 + tid] = a;
    if (tid == 0) { rec[0] = sc[0]; rec[1] = sc[1]; }
}

// ---------------- final: per-bag reduction + classifier ----------------
__global__ void mil_final(const float* __restrict__ P,
                          const float* __restrict__ Wc,
                          const float* __restrict__ bc,
                          float* __restrict__ out) {
    const int bag = blockIdx.x;
    const int tid = threadIdx.x;
    __shared__ float marr[PBAG];
    __shared__ float earr[PBAG];
    __shared__ float red[4];
    __shared__ float wred[8];

    if (tid < PBAG) marr[tid] = P[(size_t)(bag * PBAG + tid) * PSTR + 0];
    __syncthreads();
    if (tid < PBAG) {
        float v = marr[tid];
#pragma unroll
        for (int off = 1; off < 64; off <<= 1) v = fmaxf(v, __shfl_xor(v, off));
        if ((tid & 63) == 0) red[tid >> 6] = v;
    }
    __syncthreads();
    const float M = fmaxf(red[0], red[1]);
    if (tid < PBAG) {
        float e = (marr[tid] == -INFINITY) ? 0.f : __expf(marr[tid] - M);
        earr[tid] = e;
        float le = P[(size_t)(bag * PBAG + tid) * PSTR + 1] * e;
#pragma unroll
        for (int off = 1; off < 64; off <<= 1) le += __shfl_xor(le, off);
        if ((tid & 63) == 0) red[2 + (tid >> 6)] = le;
    }
    __syncthreads();
    const float L = red[2] + red[3];

    float accv = 0.f;
#pragma unroll 4
    for (int i = 0; i < PBAG; ++i)
        accv += earr[i] * P[(size_t)(bag * PBAG + i) * PSTR + 2 + tid];
    const float sr = accv / L;

    float p0 = sr * Wc[tid * 2 + 0];
    float p1 = sr * Wc[tid * 2 + 1];
#pragma unroll
    for (int off = 1; off < 64; off <<= 1) {
        p0 += __shfl_xor(p0, off);
        p1 += __shfl_xor(p1, off);
    }
    if ((tid & 63) == 0) {
        wred[(tid >> 6) * 2 + 0] = p0;
        wred[(tid >> 6) * 2 + 1] = p1;
    }
    __syncthreads();
    if (tid == 0) {
        out[bag * 2 + 0] = wred[0] + wred[2] + wred[4] + wred[6] + bc[0];
        out[bag * 2 + 1] = wred[1] + wred[3] + wred[5] + wred[7] + bc[1];
    }
}

extern "C" void kernel_launch(void* const* d_in, const int* in_sizes, int n_in,
                              void* d_out, int out_size, void* d_ws, size_t ws_size,
                              hipStream_t stream) {
    const float*         bags = (const float*)d_in[0];
    const unsigned char* mask = (const unsigned char*)d_in[1];
    const float*         W1   = (const float*)d_in[2];
    const float*         b1   = (const float*)d_in[3];
    const float*         Wv   = (const float*)d_in[4];
    const float*         bv   = (const float*)d_in[5];
    const float*         Wu   = (const float*)d_in[6];
    const float*         bu   = (const float*)d_in[7];
    const float*         ww   = (const float*)d_in[8];
    const float*         bw   = (const float*)d_in[9];
    const float*         Wc   = (const float*)d_in[10];
    const float*         bc   = (const float*)d_in[11];
    float* out = (float*)d_out;

    char* ws = (char*)d_ws;
    unsigned short* W1f = (unsigned short*)(ws);                    // 524288 B
    unsigned short* Wvf = (unsigned short*)(ws + 524288);           // 131072 B
    unsigned short* Wuf = (unsigned short*)(ws + 655360);           // 131072 B
    float*          P   = (float*)(ws + 786432);                    // 1064960 B
    unsigned short* Hg  = (unsigned short*)(ws + 1851392);          // 33554432 B

    mil_prep<<<72, 256, 0, stream>>>(W1, Wv, Wu, W1f, Wvf, Wuf);
    mil_stage1<<<NBLK, 256, 0, stream>>>(bags, b1, W1f, Hg);
    mil_stage2<<<NBLK, 256, 0, stream>>>(Hg, mask, bv, bu, ww, bw, Wvf, Wuf, P);
    mil_final<<<BB, 256, 0, stream>>>(P, Wc, bc, out);
}